// Round 1
// baseline (335.517 us; speedup 1.0000x reference)
//
#include <hip/hip_runtime.h>
#include <stdint.h>

typedef short v8s __attribute__((ext_vector_type(8)));
typedef short v4s __attribute__((ext_vector_type(4)));
typedef float v4f __attribute__((ext_vector_type(4)));

#define BM 128
#define BN 128
#define BK 64
#define LDT 72   // LDS row stride in shorts: 64 + 8 pad (144 B, 16B-aligned rows)

#define POS_INF __builtin_inff()

__device__ __forceinline__ short f2bf(float f) {
    // round-to-nearest-even fp32 -> bf16 (inputs are finite)
    uint32_t u = __builtin_bit_cast(uint32_t, f);
    u += 0x7fffu + ((u >> 16) & 1u);
    return (short)(u >> 16);
}

// Normalize centers rows (fp32 math), store bf16; pad rows [C, CP) with zeros.
// Also zeroes d_out (runs before reduce_loss on the same stream).
__global__ void prep_centers(const float* __restrict__ centers,
                             unsigned short* __restrict__ cbf,
                             int C, int D, float* __restrict__ out) {
    const int row  = blockIdx.x;
    const int lane = threadIdx.x;  // 64 threads = 1 wave
    if (row == 0 && lane == 0) out[0] = 0.0f;
    if (row >= C) {
        v4s z = {0, 0, 0, 0};
        for (int d = lane * 4; d < D; d += 256)
            *(v4s*)&cbf[(size_t)row * D + d] = z;
        return;
    }
    const float* src = centers + (size_t)row * D;
    float ss = 0.0f;
    for (int d = lane * 4; d < D; d += 256) {
        v4f f = *(const v4f*)&src[d];
        ss += f.x * f.x + f.y * f.y + f.z * f.z + f.w * f.w;
    }
    #pragma unroll
    for (int off = 32; off; off >>= 1) ss += __shfl_xor(ss, off, 64);
    const float rn = rsqrtf(ss);
    for (int d = lane * 4; d < D; d += 256) {
        v4f f = *(const v4f*)&src[d];
        v4s s;
        s.x = f2bf(f.x * rn); s.y = f2bf(f.y * rn);
        s.z = f2bf(f.z * rn); s.w = f2bf(f.w * rn);
        *(v4s*)&cbf[(size_t)row * D + d] = s;
    }
}

__global__ void convert_x(const float* __restrict__ x,
                          unsigned short* __restrict__ xbf, size_t n) {
    size_t i = ((size_t)blockIdx.x * blockDim.x + threadIdx.x) * 8;
    if (i >= n) return;
    v4f f0 = *(const v4f*)&x[i];
    v4f f1 = *(const v4f*)&x[i + 4];
    v8s s;
    s[0] = f2bf(f0.x); s[1] = f2bf(f0.y); s[2] = f2bf(f0.z); s[3] = f2bf(f0.w);
    s[4] = f2bf(f1.x); s[5] = f2bf(f1.y); s[6] = f2bf(f1.z); s[7] = f2bf(f1.w);
    *(v8s*)&xbf[i] = s;
}

// Fused GEMM + row-min epilogue.
// grid: (Bt/BM, NT). Block = 256 threads = 4 waves (2x2 wave grid, 64x64/wave).
// C/D frag layout (16x16x32 bf16): col = lane&15, row = (lane>>4)*4 + reg.
// A/B frag layout: m(or n) = lane&15, k = (lane>>4)*8 + j.
__global__ void gemm_fused(const float* __restrict__ xf,
                           const unsigned short* __restrict__ xbf, int useBf,
                           const unsigned short* __restrict__ cbf,
                           const int* __restrict__ labels,
                           float* __restrict__ pos, float* __restrict__ partial,
                           int Bt, int C, int D, int NT) {
    __shared__ short As[BM * LDT];
    __shared__ short Bs[BN * LDT];
    __shared__ int   Ls[BM];
    __shared__ float sMinW[2][BM];

    const int t    = threadIdx.x;
    const int row0 = blockIdx.x * BM;
    const int nt   = blockIdx.y;
    const int n0   = nt * BN;

    if (t < BM) Ls[t] = labels[row0 + t];

    const int lane = t & 63;
    const int wave = t >> 6;
    const int wm = wave >> 1, wn = wave & 1;
    const int l15 = lane & 15, q = lane >> 4;

    v4f acc[4][4];
    #pragma unroll
    for (int i = 0; i < 4; ++i)
        #pragma unroll
        for (int j = 0; j < 4; ++j)
            acc[i][j] = (v4f){0.f, 0.f, 0.f, 0.f};

    const int KT = D / BK;
    for (int kk = 0; kk < KT; ++kk) {
        const int k0 = kk * BK;
        // stage B tile: 128 rows x 64 k, bf16, 16B chunks
        #pragma unroll
        for (int p = 0; p < 4; ++p) {
            int r = (t >> 3) + p * 32;
            int ch = t & 7;
            v8s v = *(const v8s*)&cbf[(size_t)(n0 + r) * D + k0 + ch * 8];
            *(v8s*)&Bs[r * LDT + ch * 8] = v;
        }
        // stage A tile
        if (useBf) {
            #pragma unroll
            for (int p = 0; p < 4; ++p) {
                int r = (t >> 3) + p * 32;
                int ch = t & 7;
                v8s v = *(const v8s*)&xbf[(size_t)(row0 + r) * D + k0 + ch * 8];
                *(v8s*)&As[r * LDT + ch * 8] = v;
            }
        } else {
            #pragma unroll
            for (int p = 0; p < 8; ++p) {
                int r = (t >> 4) + p * 16;
                int c4 = t & 15;
                v4f f = *(const v4f*)&xf[(size_t)(row0 + r) * D + k0 + c4 * 4];
                v4s s;
                s.x = f2bf(f.x); s.y = f2bf(f.y);
                s.z = f2bf(f.z); s.w = f2bf(f.w);
                *(v4s*)&As[r * LDT + c4 * 4] = s;
            }
        }
        __syncthreads();
        #pragma unroll
        for (int ki = 0; ki < BK; ki += 32) {
            v8s a[4], b[4];
            #pragma unroll
            for (int i = 0; i < 4; ++i)
                a[i] = *(const v8s*)&As[(wm * 64 + i * 16 + l15) * LDT + ki + q * 8];
            #pragma unroll
            for (int j = 0; j < 4; ++j)
                b[j] = *(const v8s*)&Bs[(wn * 64 + j * 16 + l15) * LDT + ki + q * 8];
            #pragma unroll
            for (int i = 0; i < 4; ++i)
                #pragma unroll
                for (int j = 0; j < 4; ++j)
                    acc[i][j] = __builtin_amdgcn_mfma_f32_16x16x32_bf16(
                        a[i], b[j], acc[i][j], 0, 0, 0);
        }
        __syncthreads();
    }

    // Epilogue: dist = 1 - acc; extract pos at label col; row-min over cols
    // excluding label col and padding cols >= C.
    #pragma unroll
    for (int i = 0; i < 4; ++i) {
        #pragma unroll
        for (int rg = 0; rg < 4; ++rg) {
            const int row_l = wm * 64 + i * 16 + q * 4 + rg;
            const int lab = Ls[row_l];
            float m = POS_INF;
            #pragma unroll
            for (int j = 0; j < 4; ++j) {
                const int col = n0 + wn * 64 + j * 16 + l15;
                const float d = 1.0f - acc[i][j][rg];
                if (col == lab) pos[row0 + row_l] = d;
                else if (col < C) m = fminf(m, d);
            }
            m = fminf(m, __shfl_xor(m, 1, 64));
            m = fminf(m, __shfl_xor(m, 2, 64));
            m = fminf(m, __shfl_xor(m, 4, 64));
            m = fminf(m, __shfl_xor(m, 8, 64));
            if (l15 == 0) sMinW[wn][row_l] = m;
        }
    }
    __syncthreads();
    if (t < BM) {
        const float m = fminf(sMinW[0][t], sMinW[1][t]);
        partial[(size_t)nt * Bt + row0 + t] = m;
    }
}

__global__ void reduce_loss(const float* __restrict__ pos,
                            const float* __restrict__ partial,
                            int Bt, int NT, float margin,
                            float* __restrict__ out) {
    const int r = blockIdx.x * 256 + threadIdx.x;
    float h = 0.0f;
    if (r < Bt) {
        float neg = POS_INF;
        for (int tt = 0; tt < NT; ++tt)
            neg = fminf(neg, partial[(size_t)tt * Bt + r]);
        h = fmaxf(0.0f, pos[r] + margin - neg);
    }
    #pragma unroll
    for (int off = 32; off; off >>= 1) h += __shfl_down(h, off, 64);
    __shared__ float wsum[4];
    const int lane = threadIdx.x & 63, wave = threadIdx.x >> 6;
    if (lane == 0) wsum[wave] = h;
    __syncthreads();
    if (threadIdx.x == 0)
        atomicAdd(out, (wsum[0] + wsum[1] + wsum[2] + wsum[3]) * (1.0f / (float)Bt));
}

extern "C" void kernel_launch(void* const* d_in, const int* in_sizes, int n_in,
                              void* d_out, int out_size, void* d_ws, size_t ws_size,
                              hipStream_t stream) {
    const float* x       = (const float*)d_in[0];
    const int*   labels  = (const int*)d_in[1];
    const float* centers = (const float*)d_in[2];
    float* out = (float*)d_out;

    const int Bt = in_sizes[1];           // 65536
    const int D  = in_sizes[0] / Bt;      // 512
    const int C  = in_sizes[2] / D;       // 1000
    const int NT = (C + BN - 1) / BN;     // 8
    const int CP = NT * BN;               // 1024

    char* ws = (char*)d_ws;
    unsigned short* cbf = (unsigned short*)ws;          // CP*D bf16 = 1 MB
    size_t off = (size_t)CP * D * 2;
    off = (off + 255) & ~(size_t)255;
    float* pos = (float*)(ws + off);      off += (size_t)Bt * 4;       // 256 KB
    float* partial = (float*)(ws + off);  off += (size_t)NT * Bt * 4;  // 2 MB
    unsigned short* xbf = (unsigned short*)(ws + off);
    const size_t needBig = off + (size_t)Bt * D * 2;                   // +64 MB
    const int useBf = (ws_size >= needBig) ? 1 : 0;

    prep_centers<<<CP, 64, 0, stream>>>(centers, cbf, C, D, out);
    if (useBf) {
        const size_t n = (size_t)Bt * D;
        convert_x<<<(unsigned)((n / 8 + 255) / 256), 256, 0, stream>>>(x, xbf, n);
    }
    dim3 grid(Bt / BM, NT);
    gemm_fused<<<grid, 256, 0, stream>>>(x, xbf, useBf, cbf, labels, pos, partial,
                                         Bt, C, D, NT);
    reduce_loss<<<(Bt + 255) / 256, 256, 0, stream>>>(pos, partial, Bt, NT, 1.0f, out);
}

// Round 2
// 298.523 us; speedup vs baseline: 1.1239x; 1.1239x over previous
//
#include <hip/hip_runtime.h>
#include <stdint.h>

typedef short v8s __attribute__((ext_vector_type(8)));
typedef short v4s __attribute__((ext_vector_type(4)));
typedef float v4f __attribute__((ext_vector_type(4)));

#define BM 128
#define BN 128
#define BK 64          // shorts per row per k-chunk (128 B)
#define POS_INF __builtin_inff()

typedef __attribute__((address_space(3))) unsigned int lds_uint;
typedef const __attribute__((address_space(1))) unsigned int glb_uint;

__device__ __forceinline__ void load16_lds(const void* g, void* l) {
    // 16B per lane, LDS dest = wave-uniform base + lane*16
    __builtin_amdgcn_global_load_lds((glb_uint*)g, (lds_uint*)l, 16, 0, 0);
}

__device__ __forceinline__ short f2bf(float f) {
    uint32_t u = __builtin_bit_cast(uint32_t, f);
    u += 0x7fffu + ((u >> 16) & 1u);
    return (short)(u >> 16);
}

// Normalize centers rows (fp32 math), store bf16; pad rows [C, CP) with zeros.
// Also zeroes d_out.
__global__ void prep_centers(const float* __restrict__ centers,
                             unsigned short* __restrict__ cbf,
                             int C, int D, float* __restrict__ out) {
    const int row  = blockIdx.x;
    const int lane = threadIdx.x;  // 64 threads = 1 wave
    if (row == 0 && lane == 0) out[0] = 0.0f;
    if (row >= C) {
        v4s z = {0, 0, 0, 0};
        for (int d = lane * 4; d < D; d += 256)
            *(v4s*)&cbf[(size_t)row * D + d] = z;
        return;
    }
    const float* src = centers + (size_t)row * D;
    float ss = 0.0f;
    for (int d = lane * 4; d < D; d += 256) {
        v4f f = *(const v4f*)&src[d];
        ss += f.x * f.x + f.y * f.y + f.z * f.z + f.w * f.w;
    }
    #pragma unroll
    for (int off = 32; off; off >>= 1) ss += __shfl_xor(ss, off, 64);
    const float rn = rsqrtf(ss);
    for (int d = lane * 4; d < D; d += 256) {
        v4f f = *(const v4f*)&src[d];
        v4s s;
        s.x = f2bf(f.x * rn); s.y = f2bf(f.y * rn);
        s.z = f2bf(f.z * rn); s.w = f2bf(f.w * rn);
        *(v4s*)&cbf[(size_t)row * D + d] = s;
    }
}

__global__ void convert_x(const float* __restrict__ x,
                          unsigned short* __restrict__ xbf, size_t n) {
    size_t i = ((size_t)blockIdx.x * blockDim.x + threadIdx.x) * 8;
    if (i >= n) return;
    v4f f0 = *(const v4f*)&x[i];
    v4f f1 = *(const v4f*)&x[i + 4];
    v8s s;
    s[0] = f2bf(f0.x); s[1] = f2bf(f0.y); s[2] = f2bf(f0.z); s[3] = f2bf(f0.w);
    s[4] = f2bf(f1.x); s[5] = f2bf(f1.y); s[6] = f2bf(f1.z); s[7] = f2bf(f1.w);
    *(v8s*)&xbf[i] = s;
}

// Fused GEMM + row-min epilogue.
// grid: (NT, Bt/BM)  -- nt fastest for xbf L2/L3 temporal reuse.
// Block = 256 threads = 4 waves (2x2 wave grid, 64x64 per wave).
// LDS tiles are XOR-swizzled: row r, slot chunk s holds source chunk s^(r&7).
// global_load_lds writes base+lane*16 (HW-fixed); we permute the SOURCE addr.
__global__ void gemm_fused(const float* __restrict__ xf,
                           const unsigned short* __restrict__ xbf, int useBf,
                           const unsigned short* __restrict__ cbf,
                           const int* __restrict__ labels,
                           float* __restrict__ pos, float* __restrict__ partial,
                           int Bt, int C, int D, int NT) {
    __shared__ short As[BM * BK];   // 16 KB
    __shared__ short Bs[BN * BK];   // 16 KB
    __shared__ int   Ls[BM];
    __shared__ float sMinW[2][BM];

    const int t    = threadIdx.x;
    const int nt   = blockIdx.x;
    const int row0 = blockIdx.y * BM;
    const int n0   = nt * BN;

    if (t < BM) Ls[t] = labels[row0 + t];

    const int lane = t & 63;
    const int wave = t >> 6;
    const int wm = wave >> 1, wn = wave & 1;
    const int l15 = lane & 15, q = lane >> 4;

    // staging lane decomposition: 8 rows x 8 chunks per instruction
    const int rsub = lane >> 3;              // row within 8-row group
    const int csrc = (lane & 7) ^ rsub;      // swizzled source chunk

    v4f acc[4][4];
    #pragma unroll
    for (int i = 0; i < 4; ++i)
        #pragma unroll
        for (int j = 0; j < 4; ++j)
            acc[i][j] = (v4f){0.f, 0.f, 0.f, 0.f};

    const int KT = D / BK;
    for (int kk = 0; kk < KT; ++kk) {
        const int k0 = kk * BK;
        // stage B tile via global_load_lds: 4 instrs/wave (32 rows/wave)
        #pragma unroll
        for (int p = 0; p < 4; ++p) {
            const int rbase = wave * 32 + p * 8;
            const unsigned short* g =
                &cbf[(size_t)(n0 + rbase + rsub) * D + k0 + csrc * 8];
            load16_lds(g, &Bs[rbase * BK]);
        }
        // stage A tile
        if (useBf) {
            #pragma unroll
            for (int p = 0; p < 4; ++p) {
                const int rbase = wave * 32 + p * 8;
                const unsigned short* g =
                    &xbf[(size_t)(row0 + rbase + rsub) * D + k0 + csrc * 8];
                load16_lds(g, &As[rbase * BK]);
            }
        } else {
            // fp32 fallback: convert during staging, same swizzled layout
            #pragma unroll
            for (int p = 0; p < 4; ++p) {
                const int r = (t >> 3) + p * 32;
                const int cs = t & 7;
                const float* src = &xf[(size_t)(row0 + r) * D + k0 + cs * 8];
                v4f f0 = *(const v4f*)&src[0];
                v4f f1 = *(const v4f*)&src[4];
                v8s s;
                s[0] = f2bf(f0.x); s[1] = f2bf(f0.y);
                s[2] = f2bf(f0.z); s[3] = f2bf(f0.w);
                s[4] = f2bf(f1.x); s[5] = f2bf(f1.y);
                s[6] = f2bf(f1.z); s[7] = f2bf(f1.w);
                *(v8s*)&As[r * BK + (cs ^ (r & 7)) * 8] = s;
            }
        }
        __syncthreads();
        #pragma unroll
        for (int ki = 0; ki < BK; ki += 32) {
            const int cbase = ki >> 3;  // chunk base (0 or 4)
            v8s a[4], b[4];
            #pragma unroll
            for (int i = 0; i < 4; ++i) {
                const int m = wm * 64 + i * 16 + l15;
                a[i] = *(const v8s*)&As[m * BK + (((cbase + q) ^ (l15 & 7)) * 8)];
            }
            #pragma unroll
            for (int j = 0; j < 4; ++j) {
                const int n = wn * 64 + j * 16 + l15;
                b[j] = *(const v8s*)&Bs[n * BK + (((cbase + q) ^ (l15 & 7)) * 8)];
            }
            #pragma unroll
            for (int i = 0; i < 4; ++i)
                #pragma unroll
                for (int j = 0; j < 4; ++j)
                    acc[i][j] = __builtin_amdgcn_mfma_f32_16x16x32_bf16(
                        a[i], b[j], acc[i][j], 0, 0, 0);
        }
        __syncthreads();
    }

    // Epilogue: dist = 1 - acc; extract pos at label col; row-min over cols
    // excluding label col and padding cols >= C.
    #pragma unroll
    for (int i = 0; i < 4; ++i) {
        #pragma unroll
        for (int rg = 0; rg < 4; ++rg) {
            const int row_l = wm * 64 + i * 16 + q * 4 + rg;
            const int lab = Ls[row_l];
            float m = POS_INF;
            #pragma unroll
            for (int j = 0; j < 4; ++j) {
                const int col = n0 + wn * 64 + j * 16 + l15;
                const float d = 1.0f - acc[i][j][rg];
                if (col == lab) pos[row0 + row_l] = d;
                else if (col < C) m = fminf(m, d);
            }
            m = fminf(m, __shfl_xor(m, 1, 64));
            m = fminf(m, __shfl_xor(m, 2, 64));
            m = fminf(m, __shfl_xor(m, 4, 64));
            m = fminf(m, __shfl_xor(m, 8, 64));
            if (l15 == 0) sMinW[wn][row_l] = m;
        }
    }
    __syncthreads();
    if (t < BM) {
        const float m = fminf(sMinW[0][t], sMinW[1][t]);
        partial[(size_t)nt * Bt + row0 + t] = m;
    }
}

__global__ void reduce_loss(const float* __restrict__ pos,
                            const float* __restrict__ partial,
                            int Bt, int NT, float margin,
                            float* __restrict__ out) {
    const int r = blockIdx.x * 256 + threadIdx.x;
    float h = 0.0f;
    if (r < Bt) {
        float neg = POS_INF;
        for (int tt = 0; tt < NT; ++tt)
            neg = fminf(neg, partial[(size_t)tt * Bt + r]);
        h = fmaxf(0.0f, pos[r] + margin - neg);
    }
    #pragma unroll
    for (int off = 32; off; off >>= 1) h += __shfl_down(h, off, 64);
    __shared__ float wsum[4];
    const int lane = threadIdx.x & 63, wave = threadIdx.x >> 6;
    if (lane == 0) wsum[wave] = h;
    __syncthreads();
    if (threadIdx.x == 0)
        atomicAdd(out, (wsum[0] + wsum[1] + wsum[2] + wsum[3]) * (1.0f / (float)Bt));
}

extern "C" void kernel_launch(void* const* d_in, const int* in_sizes, int n_in,
                              void* d_out, int out_size, void* d_ws, size_t ws_size,
                              hipStream_t stream) {
    const float* x       = (const float*)d_in[0];
    const int*   labels  = (const int*)d_in[1];
    const float* centers = (const float*)d_in[2];
    float* out = (float*)d_out;

    const int Bt = in_sizes[1];           // 65536
    const int D  = in_sizes[0] / Bt;      // 512
    const int C  = in_sizes[2] / D;       // 1000
    const int NT = (C + BN - 1) / BN;     // 8
    const int CP = NT * BN;               // 1024

    char* ws = (char*)d_ws;
    unsigned short* cbf = (unsigned short*)ws;          // CP*D bf16 = 1 MB
    size_t off = (size_t)CP * D * 2;
    off = (off + 255) & ~(size_t)255;
    float* pos = (float*)(ws + off);      off += (size_t)Bt * 4;       // 256 KB
    float* partial = (float*)(ws + off);  off += (size_t)NT * Bt * 4;  // 2 MB
    unsigned short* xbf = (unsigned short*)(ws + off);
    const size_t needBig = off + (size_t)Bt * D * 2;                   // +64 MB
    const int useBf = (ws_size >= needBig) ? 1 : 0;

    prep_centers<<<CP, 64, 0, stream>>>(centers, cbf, C, D, out);
    if (useBf) {
        const size_t n = (size_t)Bt * D;
        convert_x<<<(unsigned)((n / 8 + 255) / 256), 256, 0, stream>>>(x, xbf, n);
    }
    dim3 grid(NT, Bt / BM);
    gemm_fused<<<grid, 256, 0, stream>>>(x, xbf, useBf, cbf, labels, pos, partial,
                                         Bt, C, D, NT);
    reduce_loss<<<(Bt + 255) / 256, 256, 0, stream>>>(pos, partial, Bt, NT, 1.0f, out);
}

// Round 3
// 290.299 us; speedup vs baseline: 1.1558x; 1.0283x over previous
//
#include <hip/hip_runtime.h>
#include <stdint.h>

typedef short v8s __attribute__((ext_vector_type(8)));
typedef short v4s __attribute__((ext_vector_type(4)));
typedef float v4f __attribute__((ext_vector_type(4)));

#define BM 128
#define BN 128
#define BK 64          // shorts per row per k-chunk (128 B)
#define POS_INF __builtin_inff()

typedef __attribute__((address_space(3))) unsigned int lds_uint;
typedef const __attribute__((address_space(1))) unsigned int glb_uint;

__device__ __forceinline__ void load16_lds(const void* g, void* l) {
    // 16B per lane, LDS dest = wave-uniform base + lane*16
    __builtin_amdgcn_global_load_lds((glb_uint*)g, (lds_uint*)l, 16, 0, 0);
}

__device__ __forceinline__ short f2bf(float f) {
    uint32_t u = __builtin_bit_cast(uint32_t, f);
    u += 0x7fffu + ((u >> 16) & 1u);
    return (short)(u >> 16);
}

// Fused prep: blocks [0, CB) normalize centers (1 row per wave, 4 rows/block)
// and pad rows [C, CP) with zeros; blocks [CB, ...) convert x fp32->bf16.
// Also zeroes d_out.
__global__ void prep(const float* __restrict__ centers,
                     unsigned short* __restrict__ cbf,
                     int C, int D, int CP, int CB,
                     const float* __restrict__ x,
                     unsigned short* __restrict__ xbf, size_t nx,
                     float* __restrict__ out) {
    const int b = blockIdx.x;
    const int t = threadIdx.x;
    if (b == 0 && t == 0) out[0] = 0.0f;
    if (b < CB) {
        const int wave = t >> 6, lane = t & 63;
        const int row = b * 4 + wave;
        if (row >= CP) return;
        if (row >= C) {
            v4s z = {0, 0, 0, 0};
            for (int d = lane * 4; d < D; d += 256)
                *(v4s*)&cbf[(size_t)row * D + d] = z;
            return;
        }
        const float* src = centers + (size_t)row * D;
        float ss = 0.0f;
        for (int d = lane * 4; d < D; d += 256) {
            v4f f = *(const v4f*)&src[d];
            ss += f.x * f.x + f.y * f.y + f.z * f.z + f.w * f.w;
        }
        #pragma unroll
        for (int off = 32; off; off >>= 1) ss += __shfl_xor(ss, off, 64);
        const float rn = rsqrtf(ss);
        for (int d = lane * 4; d < D; d += 256) {
            v4f f = *(const v4f*)&src[d];
            v4s s;
            s.x = f2bf(f.x * rn); s.y = f2bf(f.y * rn);
            s.z = f2bf(f.z * rn); s.w = f2bf(f.w * rn);
            *(v4s*)&cbf[(size_t)row * D + d] = s;
        }
    } else {
        const size_t i = ((size_t)(b - CB) * 256 + t) * 8;
        if (i >= nx) return;
        v4f f0 = *(const v4f*)&x[i];
        v4f f1 = *(const v4f*)&x[i + 4];
        v8s s;
        s[0] = f2bf(f0.x); s[1] = f2bf(f0.y); s[2] = f2bf(f0.z); s[3] = f2bf(f0.w);
        s[4] = f2bf(f1.x); s[5] = f2bf(f1.y); s[6] = f2bf(f1.z); s[7] = f2bf(f1.w);
        *(v8s*)&xbf[i] = s;
    }
}

// Fused GEMM + row-min epilogue.
// 1D grid of NB*NT blocks, XCD-swizzled: xcd = bid&7 owns row-blocks
// rowblk ≡ xcd (mod 8), and runs all NT n-tiles of a row-block consecutively
// so the A-slab stays in that XCD's L2.
// Block = 256 threads = 4 waves (2x2 wave grid, 64x64 per wave).
// LDS tiles XOR-swizzled: row r, slot chunk s holds source chunk s^(r&7);
// global_load_lds writes base+lane*16 (HW-fixed) so the SOURCE addr is permuted.
// Epilogue-only arrays (Ls, sMinW) alias As/Bs to keep LDS at exactly 32 KB
// -> 5 blocks/CU.
__global__ void gemm_fused(const float* __restrict__ xf,
                           const unsigned short* __restrict__ xbf, int useBf,
                           const unsigned short* __restrict__ cbf,
                           const int* __restrict__ labels,
                           float* __restrict__ pos, float* __restrict__ partial,
                           int Bt, int C, int D, int NT) {
    __shared__ short As[BM * BK];   // 16 KB
    __shared__ short Bs[BN * BK];   // 16 KB

    const int t   = threadIdx.x;
    const int bid = blockIdx.x;
    const int xcd = bid & 7;
    const int per = bid >> 3;
    const int rowblk = (per >> 3) * 8 + xcd;
    const int nt     = per & 7;
    const int row0 = rowblk * BM;
    const int n0   = nt * BN;

    const int lane = t & 63;
    const int wave = t >> 6;
    const int wm = wave >> 1, wn = wave & 1;
    const int l15 = lane & 15, q = lane >> 4;

    // staging lane decomposition: 8 rows x 8 chunks per instruction
    const int rsub = lane >> 3;              // row within 8-row group
    const int csrc = (lane & 7) ^ rsub;      // swizzled source chunk

    v4f acc[4][4];
    #pragma unroll
    for (int i = 0; i < 4; ++i)
        #pragma unroll
        for (int j = 0; j < 4; ++j)
            acc[i][j] = (v4f){0.f, 0.f, 0.f, 0.f};

    const int KT = D / BK;
    for (int kk = 0; kk < KT; ++kk) {
        const int k0 = kk * BK;
        // stage B tile via global_load_lds: 4 instrs/wave (32 rows/wave)
        #pragma unroll
        for (int p = 0; p < 4; ++p) {
            const int rbase = wave * 32 + p * 8;
            const unsigned short* g =
                &cbf[(size_t)(n0 + rbase + rsub) * D + k0 + csrc * 8];
            load16_lds(g, &Bs[rbase * BK]);
        }
        // stage A tile
        if (useBf) {
            #pragma unroll
            for (int p = 0; p < 4; ++p) {
                const int rbase = wave * 32 + p * 8;
                const unsigned short* g =
                    &xbf[(size_t)(row0 + rbase + rsub) * D + k0 + csrc * 8];
                load16_lds(g, &As[rbase * BK]);
            }
        } else {
            // fp32 fallback: convert during staging, same swizzled layout
            #pragma unroll
            for (int p = 0; p < 4; ++p) {
                const int r = (t >> 3) + p * 32;
                const int cs = t & 7;
                const float* src = &xf[(size_t)(row0 + r) * D + k0 + cs * 8];
                v4f f0 = *(const v4f*)&src[0];
                v4f f1 = *(const v4f*)&src[4];
                v8s s;
                s[0] = f2bf(f0.x); s[1] = f2bf(f0.y);
                s[2] = f2bf(f0.z); s[3] = f2bf(f0.w);
                s[4] = f2bf(f1.x); s[5] = f2bf(f1.y);
                s[6] = f2bf(f1.z); s[7] = f2bf(f1.w);
                *(v8s*)&As[r * BK + (cs ^ (r & 7)) * 8] = s;
            }
        }
        __syncthreads();
        #pragma unroll
        for (int ki = 0; ki < BK; ki += 32) {
            const int cbase = ki >> 3;  // chunk base (0 or 4)
            v8s a[4], b[4];
            #pragma unroll
            for (int i = 0; i < 4; ++i) {
                const int m = wm * 64 + i * 16 + l15;
                a[i] = *(const v8s*)&As[m * BK + (((cbase + q) ^ (l15 & 7)) * 8)];
            }
            #pragma unroll
            for (int j = 0; j < 4; ++j) {
                const int n = wn * 64 + j * 16 + l15;
                b[j] = *(const v8s*)&Bs[n * BK + (((cbase + q) ^ (l15 & 7)) * 8)];
            }
            #pragma unroll
            for (int i = 0; i < 4; ++i)
                #pragma unroll
                for (int j = 0; j < 4; ++j)
                    acc[i][j] = __builtin_amdgcn_mfma_f32_16x16x32_bf16(
                        a[i], b[j], acc[i][j], 0, 0, 0);
        }
        __syncthreads();
    }

    // Epilogue (As/Bs are dead now; alias them).
    int*   Ls    = (int*)As;     // [BM]
    float* sMinW = (float*)Bs;   // [2][BM]
    if (t < BM) Ls[t] = labels[row0 + t];
    __syncthreads();

    // dist = 1 - acc; extract pos at label col; row-min over cols excluding
    // label col and padding cols >= C.
    #pragma unroll
    for (int i = 0; i < 4; ++i) {
        #pragma unroll
        for (int rg = 0; rg < 4; ++rg) {
            const int row_l = wm * 64 + i * 16 + q * 4 + rg;
            const int lab = Ls[row_l];
            float m = POS_INF;
            #pragma unroll
            for (int j = 0; j < 4; ++j) {
                const int col = n0 + wn * 64 + j * 16 + l15;
                const float d = 1.0f - acc[i][j][rg];
                if (col == lab) pos[row0 + row_l] = d;
                else if (col < C) m = fminf(m, d);
            }
            m = fminf(m, __shfl_xor(m, 1, 64));
            m = fminf(m, __shfl_xor(m, 2, 64));
            m = fminf(m, __shfl_xor(m, 4, 64));
            m = fminf(m, __shfl_xor(m, 8, 64));
            if (l15 == 0) sMinW[wn * BM + row_l] = m;
        }
    }
    __syncthreads();
    if (t < BM) {
        const float m = fminf(sMinW[t], sMinW[BM + t]);
        partial[(size_t)nt * Bt + row0 + t] = m;
    }
}

__global__ void reduce_loss(const float* __restrict__ pos,
                            const float* __restrict__ partial,
                            int Bt, int NT, float margin,
                            float* __restrict__ out) {
    const int r = blockIdx.x * 256 + threadIdx.x;
    float h = 0.0f;
    if (r < Bt) {
        float neg = POS_INF;
        for (int tt = 0; tt < NT; ++tt)
            neg = fminf(neg, partial[(size_t)tt * Bt + r]);
        h = fmaxf(0.0f, pos[r] + margin - neg);
    }
    #pragma unroll
    for (int off = 32; off; off >>= 1) h += __shfl_down(h, off, 64);
    __shared__ float wsum[4];
    const int lane = threadIdx.x & 63, wave = threadIdx.x >> 6;
    if (lane == 0) wsum[wave] = h;
    __syncthreads();
    if (threadIdx.x == 0)
        atomicAdd(out, (wsum[0] + wsum[1] + wsum[2] + wsum[3]) * (1.0f / (float)Bt));
}

extern "C" void kernel_launch(void* const* d_in, const int* in_sizes, int n_in,
                              void* d_out, int out_size, void* d_ws, size_t ws_size,
                              hipStream_t stream) {
    const float* x       = (const float*)d_in[0];
    const int*   labels  = (const int*)d_in[1];
    const float* centers = (const float*)d_in[2];
    float* out = (float*)d_out;

    const int Bt = in_sizes[1];           // 65536
    const int D  = in_sizes[0] / Bt;      // 512
    const int C  = in_sizes[2] / D;       // 1000
    const int NT = (C + BN - 1) / BN;     // 8
    const int CP = NT * BN;               // 1024
    const int NB = Bt / BM;               // 512

    char* ws = (char*)d_ws;
    unsigned short* cbf = (unsigned short*)ws;          // CP*D bf16 = 1 MB
    size_t off = (size_t)CP * D * 2;
    off = (off + 255) & ~(size_t)255;
    float* pos = (float*)(ws + off);      off += (size_t)Bt * 4;       // 256 KB
    float* partial = (float*)(ws + off);  off += (size_t)NT * Bt * 4;  // 2 MB
    unsigned short* xbf = (unsigned short*)(ws + off);
    const size_t needBig = off + (size_t)Bt * D * 2;                   // +64 MB
    const int useBf = (ws_size >= needBig) ? 1 : 0;

    const size_t nx = (size_t)Bt * D;
    const int CB = CP / 4;                                // center blocks
    const int XB = useBf ? (int)((nx / 8 + 255) / 256) : 0; // convert blocks
    prep<<<CB + XB, 256, 0, stream>>>(centers, cbf, C, D, CP, CB, x, xbf, nx, out);

    gemm_fused<<<NB * NT, 256, 0, stream>>>(x, xbf, useBf, cbf, labels, pos,
                                            partial, Bt, C, D, NT);
    reduce_loss<<<(Bt + 255) / 256, 256, 0, stream>>>(pos, partial, Bt, NT, 1.0f, out);
}